// Round 1
// baseline (1018.480 us; speedup 1.0000x reference)
//
#include <hip/hip_runtime.h>
#include <math.h>

// Problem constants
#define T_TOK 8192   // B*S tokens
#define DIM   1024   // D
#define HID   2816   // H
#define NE    8      // experts
// K (top-k) = 2

#define LDT 40       // padded LDS row stride in bf16 elems (32 + 8): 80B rows -> 2-way bank alias only

typedef __attribute__((ext_vector_type(4))) float  f32x4;
typedef __attribute__((ext_vector_type(8))) __bf16 bf16x8;

__device__ __forceinline__ unsigned short f2bf(float f) {
  unsigned int u = __builtin_bit_cast(unsigned int, f);
  unsigned int r = (u + 0x7FFFu + ((u >> 16) & 1u)) >> 16;   // RTNE
  return (unsigned short)r;
}
__device__ __forceinline__ int imin(int a, int b) { return a < b ? a : b; }

// ---------------- x -> bf16 cast ----------------
__global__ __launch_bounds__(256) void cast_x_kernel(const float* __restrict__ x,
                                                     unsigned short* __restrict__ xb) {
  size_t i = ((size_t)blockIdx.x * 256 + threadIdx.x) * 8;
  float4 a = *(const float4*)(x + i);
  float4 b = *(const float4*)(x + i + 4);
  typedef __attribute__((ext_vector_type(8))) unsigned short u16x8;
  u16x8 v;
  v[0] = f2bf(a.x); v[1] = f2bf(a.y); v[2] = f2bf(a.z); v[3] = f2bf(a.w);
  v[4] = f2bf(b.x); v[5] = f2bf(b.y); v[6] = f2bf(b.z); v[7] = f2bf(b.w);
  *(u16x8*)(xb + i) = v;
}

// ------------- fp32 [E][R][C] -> bf16 [E][C][R] transpose-cast -------------
__global__ __launch_bounds__(256) void transpose_cast_kernel(const float* __restrict__ src,
                                                             unsigned short* __restrict__ dst,
                                                             int R, int C) {
  __shared__ float tile[32][33];
  int e = blockIdx.z;
  const float* s = src + (size_t)e * R * C;
  unsigned short* d = dst + (size_t)e * R * C;
  int tx = threadIdx.x & 31, ty = threadIdx.x >> 5;
  int r0 = blockIdx.y * 32, c0 = blockIdx.x * 32;
#pragma unroll
  for (int j = 0; j < 4; ++j)
    tile[ty + 8 * j][tx] = s[(size_t)(r0 + ty + 8 * j) * C + c0 + tx];
  __syncthreads();
#pragma unroll
  for (int j = 0; j < 4; ++j)
    d[(size_t)(c0 + ty + 8 * j) * R + r0 + tx] = f2bf(tile[tx][ty + 8 * j]);
}

// ---------------- router: scores (fp64), top-2, softmax, compact ----------------
__global__ __launch_bounds__(256) void router_kernel(const float* __restrict__ x,
                                                     const float* __restrict__ gw,
                                                     int* __restrict__ cnt,
                                                     int* __restrict__ idx,
                                                     float* __restrict__ wgt) {
  int wid = threadIdx.x >> 6;
  int lane = threadIdx.x & 63;
  int t = blockIdx.x * 4 + wid;
  double acc[NE];
#pragma unroll
  for (int e = 0; e < NE; ++e) acc[e] = 0.0;
  const float* xr = x + (size_t)t * DIM;
#pragma unroll 4
  for (int i = 0; i < DIM / 64; ++i) {
    int d = i * 64 + lane;
    double xv = (double)xr[d];
#pragma unroll
    for (int e = 0; e < NE; ++e) acc[e] += xv * (double)gw[e * DIM + d];
  }
#pragma unroll
  for (int e = 0; e < NE; ++e) {
#pragma unroll
    for (int off = 32; off >= 1; off >>= 1) acc[e] += __shfl_xor(acc[e], off);
  }
  if (lane == 0) {
    int e0 = 0; double s0 = acc[0];
#pragma unroll
    for (int e = 1; e < NE; ++e) if (acc[e] > s0) { s0 = acc[e]; e0 = e; }
    int e1 = -1; double s1 = -1.0e300;
#pragma unroll
    for (int e = 0; e < NE; ++e) if (e != e0 && acc[e] > s1) { s1 = acc[e]; e1 = e; }
    double w0 = 1.0 / (1.0 + exp(s1 - s0));   // softmax over {s0,s1}, s0 >= s1
    int p0 = atomicAdd(&cnt[e0], 1);
    idx[e0 * T_TOK + p0] = t; wgt[e0 * T_TOK + p0] = (float)w0;
    int p1 = atomicAdd(&cnt[e1], 1);
    idx[e1 * T_TOK + p1] = t; wgt[e1 * T_TOK + p1] = (float)(1.0 - w0);
  }
}

__global__ void offsets_kernel(const int* __restrict__ cnt, int* __restrict__ offs) {
  if (threadIdx.x == 0) {
    int s = 0;
    for (int e = 0; e < NE; ++e) { offs[e] = s; s += cnt[e]; }
  }
}

// ---------------- GEMM1: h = silu(Xg @ w1) * (Xg @ w3), bf16 out ----------------
__global__ __launch_bounds__(256) void gemm1_kernel(const unsigned short* __restrict__ xb,
                                                    const unsigned short* __restrict__ w1t,
                                                    const unsigned short* __restrict__ w3t,
                                                    const int* __restrict__ cnt,
                                                    const int* __restrict__ offs,
                                                    const int* __restrict__ idx,
                                                    unsigned short* __restrict__ hbuf) {
  int e = blockIdx.y;
  int c = cnt[e];
  int m0 = blockIdx.z * 128;
  if (m0 >= c) return;
  int n0 = blockIdx.x * 128;

  __shared__ __align__(16) unsigned short As[128 * LDT];
  __shared__ __align__(16) unsigned short B1s[128 * LDT];
  __shared__ __align__(16) unsigned short B3s[128 * LDT];

  int t = threadIdx.x;
  int wid = t >> 6, lane = t & 63;
  int wr = (wid >> 1) * 64, wc = (wid & 1) * 64;
  int lr = lane & 15, lk = (lane >> 4) * 8;

  int r1 = t >> 2, r2 = r1 + 64;
  int part = (t & 3) * 8;
  const int* idx_e = idx + e * T_TOK;
  int tokA1 = (m0 + r1 < c) ? idx_e[m0 + r1] : 0;
  int tokA2 = (m0 + r2 < c) ? idx_e[m0 + r2] : 0;
  const unsigned short* w1e = w1t + ((size_t)e * HID + n0) * DIM;
  const unsigned short* w3e = w3t + ((size_t)e * HID + n0) * DIM;

  f32x4 acc1[4][4], acc3[4][4];
#pragma unroll
  for (int i = 0; i < 4; ++i)
#pragma unroll
    for (int j = 0; j < 4; ++j) {
      acc1[i][j] = f32x4{0.f, 0.f, 0.f, 0.f};
      acc3[i][j] = f32x4{0.f, 0.f, 0.f, 0.f};
    }

  for (int k0 = 0; k0 < DIM; k0 += 32) {
    __syncthreads();
    *(uint4*)(As  + r1 * LDT + part) = *(const uint4*)(xb + (size_t)tokA1 * DIM + k0 + part);
    *(uint4*)(As  + r2 * LDT + part) = *(const uint4*)(xb + (size_t)tokA2 * DIM + k0 + part);
    *(uint4*)(B1s + r1 * LDT + part) = *(const uint4*)(w1e + (size_t)r1 * DIM + k0 + part);
    *(uint4*)(B1s + r2 * LDT + part) = *(const uint4*)(w1e + (size_t)r2 * DIM + k0 + part);
    *(uint4*)(B3s + r1 * LDT + part) = *(const uint4*)(w3e + (size_t)r1 * DIM + k0 + part);
    *(uint4*)(B3s + r2 * LDT + part) = *(const uint4*)(w3e + (size_t)r2 * DIM + k0 + part);
    __syncthreads();

    bf16x8 a[4], b1[4], b3[4];
#pragma unroll
    for (int f = 0; f < 4; ++f) {
      a[f]  = *(const bf16x8*)(As  + (wr + f * 16 + lr) * LDT + lk);
      b1[f] = *(const bf16x8*)(B1s + (wc + f * 16 + lr) * LDT + lk);
      b3[f] = *(const bf16x8*)(B3s + (wc + f * 16 + lr) * LDT + lk);
    }
#pragma unroll
    for (int i = 0; i < 4; ++i)
#pragma unroll
      for (int j = 0; j < 4; ++j) {
        acc1[i][j] = __builtin_amdgcn_mfma_f32_16x16x32_bf16(a[i], b1[j], acc1[i][j], 0, 0, 0);
        acc3[i][j] = __builtin_amdgcn_mfma_f32_16x16x32_bf16(a[i], b3[j], acc3[i][j], 0, 0, 0);
      }
  }

  int base = offs[e];
#pragma unroll
  for (int i = 0; i < 4; ++i)
#pragma unroll
    for (int q = 0; q < 4; ++q) {
      int pl = m0 + wr + i * 16 + (lane >> 4) * 4 + q;
      if (pl >= c) continue;
      unsigned short* hrow = hbuf + (size_t)(base + pl) * HID + n0 + wc + (lane & 15);
#pragma unroll
      for (int j = 0; j < 4; ++j) {
        float v1 = acc1[i][j][q];
        float v3 = acc3[i][j][q];
        float hv = v1 / (1.0f + __expf(-v1)) * v3;   // silu(v1) * v3
        hrow[j * 16] = f2bf(hv);
      }
    }
}

// ---------------- GEMM2: out[tok] += w * (h @ w2) ----------------
__global__ __launch_bounds__(256) void gemm2_kernel(const unsigned short* __restrict__ hbuf,
                                                    const unsigned short* __restrict__ w2t,
                                                    const int* __restrict__ cnt,
                                                    const int* __restrict__ offs,
                                                    const int* __restrict__ idx,
                                                    const float* __restrict__ wgt,
                                                    float* __restrict__ out) {
  int e = blockIdx.y;
  int c = cnt[e];
  int m0 = blockIdx.z * 128;
  if (m0 >= c) return;
  int n0 = blockIdx.x * 128;

  __shared__ __align__(16) unsigned short As[128 * LDT];
  __shared__ __align__(16) unsigned short Bs[128 * LDT];

  int t = threadIdx.x;
  int wid = t >> 6, lane = t & 63;
  int wr = (wid >> 1) * 64, wc = (wid & 1) * 64;
  int lr = lane & 15, lk = (lane >> 4) * 8;
  int base = offs[e];

  int r1 = t >> 2, r2 = r1 + 64;
  int part = (t & 3) * 8;
  size_t ha1 = (size_t)imin(base + m0 + r1, 2 * T_TOK - 1) * HID;
  size_t ha2 = (size_t)imin(base + m0 + r2, 2 * T_TOK - 1) * HID;
  const unsigned short* w2e = w2t + ((size_t)e * DIM + n0) * HID;

  f32x4 acc[4][4];
#pragma unroll
  for (int i = 0; i < 4; ++i)
#pragma unroll
    for (int j = 0; j < 4; ++j) acc[i][j] = f32x4{0.f, 0.f, 0.f, 0.f};

  for (int k0 = 0; k0 < HID; k0 += 32) {
    __syncthreads();
    *(uint4*)(As + r1 * LDT + part) = *(const uint4*)(hbuf + ha1 + k0 + part);
    *(uint4*)(As + r2 * LDT + part) = *(const uint4*)(hbuf + ha2 + k0 + part);
    *(uint4*)(Bs + r1 * LDT + part) = *(const uint4*)(w2e + (size_t)r1 * HID + k0 + part);
    *(uint4*)(Bs + r2 * LDT + part) = *(const uint4*)(w2e + (size_t)r2 * HID + k0 + part);
    __syncthreads();

    bf16x8 a[4], b[4];
#pragma unroll
    for (int f = 0; f < 4; ++f) {
      a[f] = *(const bf16x8*)(As + (wr + f * 16 + lr) * LDT + lk);
      b[f] = *(const bf16x8*)(Bs + (wc + f * 16 + lr) * LDT + lk);
    }
#pragma unroll
    for (int i = 0; i < 4; ++i)
#pragma unroll
      for (int j = 0; j < 4; ++j)
        acc[i][j] = __builtin_amdgcn_mfma_f32_16x16x32_bf16(a[i], b[j], acc[i][j], 0, 0, 0);
  }

  const int* idx_e = idx + e * T_TOK;
  const float* wgt_e = wgt + e * T_TOK;
#pragma unroll
  for (int i = 0; i < 4; ++i)
#pragma unroll
    for (int q = 0; q < 4; ++q) {
      int pl = m0 + wr + i * 16 + (lane >> 4) * 4 + q;
      if (pl >= c) continue;
      int tok = idx_e[pl];
      float w = wgt_e[pl];
      float* orow = out + (size_t)tok * DIM + n0 + wc + (lane & 15);
#pragma unroll
      for (int j = 0; j < 4; ++j)
        atomicAdd(orow + j * 16, w * acc[i][j][q]);
    }
}

extern "C" void kernel_launch(void* const* d_in, const int* in_sizes, int n_in,
                              void* d_out, int out_size, void* d_ws, size_t ws_size,
                              hipStream_t stream) {
  const float* x  = (const float*)d_in[0];
  const float* gw = (const float*)d_in[1];
  const float* w1 = (const float*)d_in[2];
  const float* w2 = (const float*)d_in[3];
  const float* w3 = (const float*)d_in[4];
  float* out = (float*)d_out;

  // Workspace layout (~248 MB total)
  char* ws = (char*)d_ws;
  size_t off = 0;
  auto alloc = [&](size_t bytes) {
    char* p = ws + off;
    off += (bytes + 255) & ~(size_t)255;
    return p;
  };
  unsigned short* xb  = (unsigned short*)alloc((size_t)T_TOK * DIM * 2);       // 16.8 MB
  unsigned short* w1t = (unsigned short*)alloc((size_t)NE * DIM * HID * 2);    // 46.1 MB  [E][H][D]
  unsigned short* w3t = (unsigned short*)alloc((size_t)NE * DIM * HID * 2);    // 46.1 MB  [E][H][D]
  unsigned short* w2t = (unsigned short*)alloc((size_t)NE * DIM * HID * 2);    // 46.1 MB  [E][D][H]
  unsigned short* hb  = (unsigned short*)alloc((size_t)2 * T_TOK * HID * 2);   // 92.3 MB
  int*   cnt  = (int*)alloc(NE * sizeof(int));
  int*   offs = (int*)alloc(NE * sizeof(int));
  int*   idx  = (int*)alloc((size_t)NE * T_TOK * sizeof(int));
  float* wgt  = (float*)alloc((size_t)NE * T_TOK * sizeof(float));

  hipMemsetAsync(d_out, 0, (size_t)out_size * sizeof(float), stream);
  hipMemsetAsync(cnt, 0, NE * sizeof(int), stream);

  cast_x_kernel<<<(T_TOK * DIM) / (256 * 8), 256, 0, stream>>>(x, xb);
  transpose_cast_kernel<<<dim3(HID / 32, DIM / 32, NE), 256, 0, stream>>>(w1, w1t, DIM, HID);
  transpose_cast_kernel<<<dim3(HID / 32, DIM / 32, NE), 256, 0, stream>>>(w3, w3t, DIM, HID);
  transpose_cast_kernel<<<dim3(DIM / 32, HID / 32, NE), 256, 0, stream>>>(w2, w2t, HID, DIM);
  router_kernel<<<T_TOK / 4, 256, 0, stream>>>(x, gw, cnt, idx, wgt);
  offsets_kernel<<<1, 64, 0, stream>>>(cnt, offs);

  gemm1_kernel<<<dim3(HID / 128, NE, T_TOK / 128), 256, 0, stream>>>(xb, w1t, w3t, cnt, offs, idx, hb);
  gemm2_kernel<<<dim3(DIM / 128, NE, T_TOK / 128), 256, 0, stream>>>(hb, w2t, cnt, offs, idx, wgt, out);
}

// Round 2
// 930.813 us; speedup vs baseline: 1.0942x; 1.0942x over previous
//
#include <hip/hip_runtime.h>
#include <math.h>

// Problem constants
#define T_TOK 8192   // B*S tokens
#define DIM   1024   // D
#define HID   2816   // H
#define NE    8      // experts
// K (top-k) = 2

typedef __attribute__((ext_vector_type(4))) float  f32x4;
typedef __attribute__((ext_vector_type(8))) __bf16 bf16x8;

__device__ __forceinline__ unsigned short f2bf(float f) {
  unsigned int u = __builtin_bit_cast(unsigned int, f);
  unsigned int r = (u + 0x7FFFu + ((u >> 16) & 1u)) >> 16;   // RTNE
  return (unsigned short)r;
}
__device__ __forceinline__ int imin(int a, int b) { return a < b ? a : b; }

// global -> LDS direct DMA, 16B per lane. LDS dest = wave-uniform base + lane*16.
typedef const __attribute__((address_space(1))) void gvoid_t;
typedef __attribute__((address_space(3))) void svoid_t;
__device__ __forceinline__ void g2l16(const void* g, void* l) {
  __builtin_amdgcn_global_load_lds((gvoid_t*)g, (svoid_t*)l, 16, 0, 0);
}

// ---------------- x -> bf16 cast ----------------
__global__ __launch_bounds__(256) void cast_x_kernel(const float* __restrict__ x,
                                                     unsigned short* __restrict__ xb) {
  size_t i = ((size_t)blockIdx.x * 256 + threadIdx.x) * 8;
  float4 a = *(const float4*)(x + i);
  float4 b = *(const float4*)(x + i + 4);
  typedef __attribute__((ext_vector_type(8))) unsigned short u16x8;
  u16x8 v;
  v[0] = f2bf(a.x); v[1] = f2bf(a.y); v[2] = f2bf(a.z); v[3] = f2bf(a.w);
  v[4] = f2bf(b.x); v[5] = f2bf(b.y); v[6] = f2bf(b.z); v[7] = f2bf(b.w);
  *(u16x8*)(xb + i) = v;
}

// ------------- fp32 [E][R][C] -> bf16 [E][C][R] transpose-cast -------------
__global__ __launch_bounds__(256) void transpose_cast_kernel(const float* __restrict__ src,
                                                             unsigned short* __restrict__ dst,
                                                             int R, int C) {
  __shared__ float tile[32][33];
  int e = blockIdx.z;
  const float* s = src + (size_t)e * R * C;
  unsigned short* d = dst + (size_t)e * R * C;
  int tx = threadIdx.x & 31, ty = threadIdx.x >> 5;
  int r0 = blockIdx.y * 32, c0 = blockIdx.x * 32;
#pragma unroll
  for (int j = 0; j < 4; ++j)
    tile[ty + 8 * j][tx] = s[(size_t)(r0 + ty + 8 * j) * C + c0 + tx];
  __syncthreads();
#pragma unroll
  for (int j = 0; j < 4; ++j)
    d[(size_t)(c0 + ty + 8 * j) * R + r0 + tx] = f2bf(tile[tx][ty + 8 * j]);
}

// ---------------- router: scores (fp64), top-2, softmax, compact ----------------
__global__ __launch_bounds__(256) void router_kernel(const float* __restrict__ x,
                                                     const float* __restrict__ gw,
                                                     int* __restrict__ cnt,
                                                     int* __restrict__ idx,
                                                     float* __restrict__ wgt) {
  int wid = threadIdx.x >> 6;
  int lane = threadIdx.x & 63;
  int t = blockIdx.x * 4 + wid;
  double acc[NE];
#pragma unroll
  for (int e = 0; e < NE; ++e) acc[e] = 0.0;
  const float* xr = x + (size_t)t * DIM;
#pragma unroll 4
  for (int i = 0; i < DIM / 64; ++i) {
    int d = i * 64 + lane;
    double xv = (double)xr[d];
#pragma unroll
    for (int e = 0; e < NE; ++e) acc[e] += xv * (double)gw[e * DIM + d];
  }
#pragma unroll
  for (int e = 0; e < NE; ++e) {
#pragma unroll
    for (int off = 32; off >= 1; off >>= 1) acc[e] += __shfl_xor(acc[e], off);
  }
  if (lane == 0) {
    int e0 = 0; double s0 = acc[0];
#pragma unroll
    for (int e = 1; e < NE; ++e) if (acc[e] > s0) { s0 = acc[e]; e0 = e; }
    int e1 = -1; double s1 = -1.0e300;
#pragma unroll
    for (int e = 0; e < NE; ++e) if (e != e0 && acc[e] > s1) { s1 = acc[e]; e1 = e; }
    double w0 = 1.0 / (1.0 + exp(s1 - s0));   // softmax over {s0,s1}, s0 >= s1
    int p0 = atomicAdd(&cnt[e0], 1);
    idx[e0 * T_TOK + p0] = t; wgt[e0 * T_TOK + p0] = (float)w0;
    int p1 = atomicAdd(&cnt[e1], 1);
    idx[e1 * T_TOK + p1] = t; wgt[e1 * T_TOK + p1] = (float)(1.0 - w0);
  }
}

__global__ void offsets_kernel(const int* __restrict__ cnt, int* __restrict__ offs) {
  if (threadIdx.x == 0) {
    int s = 0;
    for (int e = 0; e < NE; ++e) { offs[e] = s; s += cnt[e]; }
  }
}

// ---------------- GEMM1: h = silu(Xg @ w1) * (Xg @ w3), bf16 out ----------------
// m97 structure: global_load_lds 16B staging, linear [128][32] LDS, ds_read_b128.
__global__ __launch_bounds__(256) void gemm1_kernel(const unsigned short* __restrict__ xb,
                                                    const unsigned short* __restrict__ w1t,
                                                    const unsigned short* __restrict__ w3t,
                                                    const int* __restrict__ cnt,
                                                    const int* __restrict__ offs,
                                                    const int* __restrict__ idx,
                                                    unsigned short* __restrict__ hbuf) {
  int e = blockIdx.y;
  int c = cnt[e];
  int m0 = blockIdx.z * 128;
  if (m0 >= c) return;
  int n0 = blockIdx.x * 128;

  __shared__ __align__(16) unsigned short As[128 * 32];
  __shared__ __align__(16) unsigned short B1s[128 * 32];
  __shared__ __align__(16) unsigned short B3s[128 * 32];

  int t = threadIdx.x;
  int wid = t >> 6, lane = t & 63;
  int wr = (wid >> 1) * 64, wc = (wid & 1) * 64;
  int lr = lane & 15, lk = (lane >> 4) * 8;

  // staging: wave `wid` owns rows [wid*32, wid*32+32), 2 DMA instrs of 16 rows
  int sr0 = wid * 32 + (lane >> 2);
  int sr1 = sr0 + 16;
  int sb = (lane & 3) * 8;    // elem offset within 32-elem row
  const int* idx_e = idx + e * T_TOK;
  int tokA0 = (m0 + sr0 < c) ? idx_e[m0 + sr0] : 0;
  int tokA1 = (m0 + sr1 < c) ? idx_e[m0 + sr1] : 0;
  const unsigned short* aG0 = xb + (size_t)tokA0 * DIM + sb;
  const unsigned short* aG1 = xb + (size_t)tokA1 * DIM + sb;
  const unsigned short* w1e = w1t + ((size_t)e * HID + n0) * DIM;
  const unsigned short* w3e = w3t + ((size_t)e * HID + n0) * DIM;
  const unsigned short* b1G0 = w1e + (size_t)sr0 * DIM + sb;
  const unsigned short* b1G1 = w1e + (size_t)sr1 * DIM + sb;
  const unsigned short* b3G0 = w3e + (size_t)sr0 * DIM + sb;
  const unsigned short* b3G1 = w3e + (size_t)sr1 * DIM + sb;
  unsigned short* lA0 = As + wid * 1024;         // (wid*2+0)*512 elems
  unsigned short* lA1 = As + wid * 1024 + 512;
  unsigned short* lB10 = B1s + wid * 1024;
  unsigned short* lB11 = B1s + wid * 1024 + 512;
  unsigned short* lB30 = B3s + wid * 1024;
  unsigned short* lB31 = B3s + wid * 1024 + 512;

  f32x4 acc1[4][4], acc3[4][4];
#pragma unroll
  for (int i = 0; i < 4; ++i)
#pragma unroll
    for (int j = 0; j < 4; ++j) {
      acc1[i][j] = f32x4{0.f, 0.f, 0.f, 0.f};
      acc3[i][j] = f32x4{0.f, 0.f, 0.f, 0.f};
    }

  for (int k0 = 0; k0 < DIM; k0 += 32) {
    __syncthreads();
    g2l16(aG0 + k0, lA0);
    g2l16(aG1 + k0, lA1);
    g2l16(b1G0 + k0, lB10);
    g2l16(b1G1 + k0, lB11);
    g2l16(b3G0 + k0, lB30);
    g2l16(b3G1 + k0, lB31);
    __syncthreads();   // drains vmcnt before barrier (compiler-inserted)

    bf16x8 a[4], b1[4], b3[4];
#pragma unroll
    for (int f = 0; f < 4; ++f) {
      a[f]  = *(const bf16x8*)(As  + (wr + f * 16 + lr) * 32 + lk);
      b1[f] = *(const bf16x8*)(B1s + (wc + f * 16 + lr) * 32 + lk);
      b3[f] = *(const bf16x8*)(B3s + (wc + f * 16 + lr) * 32 + lk);
    }
#pragma unroll
    for (int i = 0; i < 4; ++i)
#pragma unroll
      for (int j = 0; j < 4; ++j) {
        acc1[i][j] = __builtin_amdgcn_mfma_f32_16x16x32_bf16(a[i], b1[j], acc1[i][j], 0, 0, 0);
        acc3[i][j] = __builtin_amdgcn_mfma_f32_16x16x32_bf16(a[i], b3[j], acc3[i][j], 0, 0, 0);
      }
  }

  int base = offs[e];
#pragma unroll
  for (int i = 0; i < 4; ++i)
#pragma unroll
    for (int q = 0; q < 4; ++q) {
      int pl = m0 + wr + i * 16 + (lane >> 4) * 4 + q;
      if (pl >= c) continue;
      unsigned short* hrow = hbuf + (size_t)(base + pl) * HID + n0 + wc + (lane & 15);
#pragma unroll
      for (int j = 0; j < 4; ++j) {
        float v1 = acc1[i][j][q];
        float v3 = acc3[i][j][q];
        float hv = v1 / (1.0f + __expf(-v1)) * v3;   // silu(v1) * v3
        hrow[j * 16] = f2bf(hv);
      }
    }
}

// ---------------- GEMM2: out[tok] += w * (h @ w2) ----------------
__global__ __launch_bounds__(256) void gemm2_kernel(const unsigned short* __restrict__ hbuf,
                                                    const unsigned short* __restrict__ w2t,
                                                    const int* __restrict__ cnt,
                                                    const int* __restrict__ offs,
                                                    const int* __restrict__ idx,
                                                    const float* __restrict__ wgt,
                                                    float* __restrict__ out) {
  int e = blockIdx.y;
  int c = cnt[e];
  int m0 = blockIdx.z * 128;
  if (m0 >= c) return;
  int n0 = blockIdx.x * 128;

  __shared__ __align__(16) unsigned short As[128 * 32];
  __shared__ __align__(16) unsigned short Bs[128 * 32];

  int t = threadIdx.x;
  int wid = t >> 6, lane = t & 63;
  int wr = (wid >> 1) * 64, wc = (wid & 1) * 64;
  int lr = lane & 15, lk = (lane >> 4) * 8;
  int base = offs[e];

  int sr0 = wid * 32 + (lane >> 2);
  int sr1 = sr0 + 16;
  int sb = (lane & 3) * 8;
  size_t ha0 = (size_t)imin(base + m0 + sr0, 2 * T_TOK - 1) * HID;
  size_t ha1 = (size_t)imin(base + m0 + sr1, 2 * T_TOK - 1) * HID;
  const unsigned short* aG0 = hbuf + ha0 + sb;
  const unsigned short* aG1 = hbuf + ha1 + sb;
  const unsigned short* w2e = w2t + ((size_t)e * DIM + n0) * HID;
  const unsigned short* bG0 = w2e + (size_t)sr0 * HID + sb;
  const unsigned short* bG1 = w2e + (size_t)sr1 * HID + sb;
  unsigned short* lA0 = As + wid * 1024;
  unsigned short* lA1 = As + wid * 1024 + 512;
  unsigned short* lB0 = Bs + wid * 1024;
  unsigned short* lB1 = Bs + wid * 1024 + 512;

  f32x4 acc[4][4];
#pragma unroll
  for (int i = 0; i < 4; ++i)
#pragma unroll
    for (int j = 0; j < 4; ++j) acc[i][j] = f32x4{0.f, 0.f, 0.f, 0.f};

  for (int k0 = 0; k0 < HID; k0 += 32) {
    __syncthreads();
    g2l16(aG0 + k0, lA0);
    g2l16(aG1 + k0, lA1);
    g2l16(bG0 + k0, lB0);
    g2l16(bG1 + k0, lB1);
    __syncthreads();

    bf16x8 a[4], b[4];
#pragma unroll
    for (int f = 0; f < 4; ++f) {
      a[f] = *(const bf16x8*)(As + (wr + f * 16 + lr) * 32 + lk);
      b[f] = *(const bf16x8*)(Bs + (wc + f * 16 + lr) * 32 + lk);
    }
#pragma unroll
    for (int i = 0; i < 4; ++i)
#pragma unroll
      for (int j = 0; j < 4; ++j)
        acc[i][j] = __builtin_amdgcn_mfma_f32_16x16x32_bf16(a[i], b[j], acc[i][j], 0, 0, 0);
  }

  const int* idx_e = idx + e * T_TOK;
  const float* wgt_e = wgt + e * T_TOK;
#pragma unroll
  for (int i = 0; i < 4; ++i)
#pragma unroll
    for (int q = 0; q < 4; ++q) {
      int pl = m0 + wr + i * 16 + (lane >> 4) * 4 + q;
      if (pl >= c) continue;
      int tok = idx_e[pl];
      float w = wgt_e[pl];
      float* orow = out + (size_t)tok * DIM + n0 + wc + (lane & 15);
#pragma unroll
      for (int j = 0; j < 4; ++j)
        atomicAdd(orow + j * 16, w * acc[i][j][q]);
    }
}

extern "C" void kernel_launch(void* const* d_in, const int* in_sizes, int n_in,
                              void* d_out, int out_size, void* d_ws, size_t ws_size,
                              hipStream_t stream) {
  const float* x  = (const float*)d_in[0];
  const float* gw = (const float*)d_in[1];
  const float* w1 = (const float*)d_in[2];
  const float* w2 = (const float*)d_in[3];
  const float* w3 = (const float*)d_in[4];
  float* out = (float*)d_out;

  // Workspace layout (~248 MB total)
  char* ws = (char*)d_ws;
  size_t off = 0;
  auto alloc = [&](size_t bytes) {
    char* p = ws + off;
    off += (bytes + 255) & ~(size_t)255;
    return p;
  };
  unsigned short* xb  = (unsigned short*)alloc((size_t)T_TOK * DIM * 2);       // 16.8 MB
  unsigned short* w1t = (unsigned short*)alloc((size_t)NE * DIM * HID * 2);    // 46.1 MB  [E][H][D]
  unsigned short* w3t = (unsigned short*)alloc((size_t)NE * DIM * HID * 2);    // 46.1 MB  [E][H][D]
  unsigned short* w2t = (unsigned short*)alloc((size_t)NE * DIM * HID * 2);    // 46.1 MB  [E][D][H]
  unsigned short* hb  = (unsigned short*)alloc((size_t)2 * T_TOK * HID * 2);   // 92.3 MB
  int*   cnt  = (int*)alloc(NE * sizeof(int));
  int*   offs = (int*)alloc(NE * sizeof(int));
  int*   idx  = (int*)alloc((size_t)NE * T_TOK * sizeof(int));
  float* wgt  = (float*)alloc((size_t)NE * T_TOK * sizeof(float));

  hipMemsetAsync(d_out, 0, (size_t)out_size * sizeof(float), stream);
  hipMemsetAsync(cnt, 0, NE * sizeof(int), stream);

  cast_x_kernel<<<(T_TOK * DIM) / (256 * 8), 256, 0, stream>>>(x, xb);
  transpose_cast_kernel<<<dim3(HID / 32, DIM / 32, NE), 256, 0, stream>>>(w1, w1t, DIM, HID);
  transpose_cast_kernel<<<dim3(HID / 32, DIM / 32, NE), 256, 0, stream>>>(w3, w3t, DIM, HID);
  transpose_cast_kernel<<<dim3(DIM / 32, HID / 32, NE), 256, 0, stream>>>(w2, w2t, HID, DIM);
  router_kernel<<<T_TOK / 4, 256, 0, stream>>>(x, gw, cnt, idx, wgt);
  offsets_kernel<<<1, 64, 0, stream>>>(cnt, offs);

  gemm1_kernel<<<dim3(HID / 128, NE, T_TOK / 128), 256, 0, stream>>>(xb, w1t, w3t, cnt, offs, idx, hb);
  gemm2_kernel<<<dim3(DIM / 128, NE, T_TOK / 128), 256, 0, stream>>>(hb, w2t, cnt, offs, idx, wgt, out);
}

// Round 3
// 889.255 us; speedup vs baseline: 1.1453x; 1.0467x over previous
//
#include <hip/hip_runtime.h>
#include <math.h>

// Problem constants
#define T_TOK 8192   // B*S tokens
#define DIM   1024   // D
#define HID   2816   // H
#define NE    8      // experts
// K (top-k) = 2

typedef __attribute__((ext_vector_type(4))) float  f32x4;
typedef __attribute__((ext_vector_type(8))) __bf16 bf16x8;

__device__ __forceinline__ unsigned short f2bf(float f) {
  unsigned int u = __builtin_bit_cast(unsigned int, f);
  unsigned int r = (u + 0x7FFFu + ((u >> 16) & 1u)) >> 16;   // RTNE
  return (unsigned short)r;
}
__device__ __forceinline__ int imin(int a, int b) { return a < b ? a : b; }

// global -> LDS direct DMA, 16B per lane. LDS dest = wave-uniform base + lane*16.
typedef const __attribute__((address_space(1))) void gvoid_t;
typedef __attribute__((address_space(3))) void svoid_t;
__device__ __forceinline__ void g2l16(const void* g, void* l) {
  __builtin_amdgcn_global_load_lds((gvoid_t*)g, (svoid_t*)l, 16, 0, 0);
}

// ---------------- x -> bf16 cast ----------------
__global__ __launch_bounds__(256) void cast_x_kernel(const float* __restrict__ x,
                                                     unsigned short* __restrict__ xb) {
  size_t i = ((size_t)blockIdx.x * 256 + threadIdx.x) * 8;
  float4 a = *(const float4*)(x + i);
  float4 b = *(const float4*)(x + i + 4);
  typedef __attribute__((ext_vector_type(8))) unsigned short u16x8;
  u16x8 v;
  v[0] = f2bf(a.x); v[1] = f2bf(a.y); v[2] = f2bf(a.z); v[3] = f2bf(a.w);
  v[4] = f2bf(b.x); v[5] = f2bf(b.y); v[6] = f2bf(b.z); v[7] = f2bf(b.w);
  *(u16x8*)(xb + i) = v;
}

// ------------- fp32 [E][R][C] -> bf16 [E][C][R] transpose-cast -------------
__global__ __launch_bounds__(256) void transpose_cast_kernel(const float* __restrict__ src,
                                                             unsigned short* __restrict__ dst,
                                                             int R, int C) {
  __shared__ float tile[32][33];
  int e = blockIdx.z;
  const float* s = src + (size_t)e * R * C;
  unsigned short* d = dst + (size_t)e * R * C;
  int tx = threadIdx.x & 31, ty = threadIdx.x >> 5;
  int r0 = blockIdx.y * 32, c0 = blockIdx.x * 32;
#pragma unroll
  for (int j = 0; j < 4; ++j)
    tile[ty + 8 * j][tx] = s[(size_t)(r0 + ty + 8 * j) * C + c0 + tx];
  __syncthreads();
#pragma unroll
  for (int j = 0; j < 4; ++j)
    d[(size_t)(c0 + ty + 8 * j) * R + r0 + tx] = f2bf(tile[tx][ty + 8 * j]);
}

// ---------------- router: scores (fp64), top-2, softmax, compact ----------------
__global__ __launch_bounds__(256) void router_kernel(const float* __restrict__ x,
                                                     const float* __restrict__ gw,
                                                     int* __restrict__ cnt,
                                                     int* __restrict__ idx,
                                                     float* __restrict__ wgt) {
  int wid = threadIdx.x >> 6;
  int lane = threadIdx.x & 63;
  int t = blockIdx.x * 4 + wid;
  double acc[NE];
#pragma unroll
  for (int e = 0; e < NE; ++e) acc[e] = 0.0;
  const float* xr = x + (size_t)t * DIM;
#pragma unroll 4
  for (int i = 0; i < DIM / 64; ++i) {
    int d = i * 64 + lane;
    double xv = (double)xr[d];
#pragma unroll
    for (int e = 0; e < NE; ++e) acc[e] += xv * (double)gw[e * DIM + d];
  }
#pragma unroll
  for (int e = 0; e < NE; ++e) {
#pragma unroll
    for (int off = 32; off >= 1; off >>= 1) acc[e] += __shfl_xor(acc[e], off);
  }
  if (lane == 0) {
    int e0 = 0; double s0 = acc[0];
#pragma unroll
    for (int e = 1; e < NE; ++e) if (acc[e] > s0) { s0 = acc[e]; e0 = e; }
    int e1 = -1; double s1 = -1.0e300;
#pragma unroll
    for (int e = 0; e < NE; ++e) if (e != e0 && acc[e] > s1) { s1 = acc[e]; e1 = e; }
    double w0 = 1.0 / (1.0 + exp(s1 - s0));   // softmax over {s0,s1}, s0 >= s1
    int p0 = atomicAdd(&cnt[e0], 1);
    idx[e0 * T_TOK + p0] = t; wgt[e0 * T_TOK + p0] = (float)w0;
    int p1 = atomicAdd(&cnt[e1], 1);
    idx[e1 * T_TOK + p1] = t; wgt[e1 * T_TOK + p1] = (float)(1.0 - w0);
  }
}

__global__ void offsets_kernel(const int* __restrict__ cnt, int* __restrict__ offs) {
  if (threadIdx.x == 0) {
    int s = 0;
    for (int e = 0; e < NE; ++e) { offs[e] = s; s += cnt[e]; }
  }
}

// ---------------- GEMM1: h = silu(Xg @ w1) * (Xg @ w3), bf16 out ----------------
// 2-phase double-buffered: stage(t+1) issued before compute(t); one barrier/K-step.
// Expert-per-XCD: e = bid&7, m fastest within n so B n-slice stays L2-resident.
__global__ __launch_bounds__(256) void gemm1_kernel(const unsigned short* __restrict__ xb,
                                                    const unsigned short* __restrict__ w1t,
                                                    const unsigned short* __restrict__ w3t,
                                                    const int* __restrict__ cnt,
                                                    const int* __restrict__ offs,
                                                    const int* __restrict__ idx,
                                                    unsigned short* __restrict__ hbuf) {
  int bid = blockIdx.x;
  int e = bid & 7;
  int g = bid >> 3;
  int n0 = (g >> 6) * 128;        // 22 n-tiles, slow
  int m0 = (g & 63) * 128;        // 64 m-slots, fast (early exit past c)
  int c = cnt[e];
  if (m0 >= c) return;

  __shared__ __align__(16) unsigned short As[2 * 4096];
  __shared__ __align__(16) unsigned short B1s[2 * 4096];
  __shared__ __align__(16) unsigned short B3s[2 * 4096];

  int t = threadIdx.x;
  int wid = t >> 6, lane = t & 63;
  int wr = (wid >> 1) * 64, wc = (wid & 1) * 64;
  int lr = lane & 15, lk = (lane >> 4) * 8;

  // staging: wave `wid` owns rows [wid*32, wid*32+32), 2 DMA instrs of 16 rows
  int sr0 = wid * 32 + (lane >> 2);
  int sr1 = sr0 + 16;
  int sb = (lane & 3) * 8;    // elem offset within 32-elem row
  const int* idx_e = idx + e * T_TOK;
  int tokA0 = (m0 + sr0 < c) ? idx_e[m0 + sr0] : 0;
  int tokA1 = (m0 + sr1 < c) ? idx_e[m0 + sr1] : 0;
  const unsigned short* aG0 = xb + (size_t)tokA0 * DIM + sb;
  const unsigned short* aG1 = xb + (size_t)tokA1 * DIM + sb;
  const unsigned short* w1e = w1t + ((size_t)e * HID + n0) * DIM;
  const unsigned short* w3e = w3t + ((size_t)e * HID + n0) * DIM;
  const unsigned short* b1G0 = w1e + (size_t)sr0 * DIM + sb;
  const unsigned short* b1G1 = w1e + (size_t)sr1 * DIM + sb;
  const unsigned short* b3G0 = w3e + (size_t)sr0 * DIM + sb;
  const unsigned short* b3G1 = w3e + (size_t)sr1 * DIM + sb;
  int lofs0 = wid * 1024;          // elems within a 4096-elem buffer
  int lofs1 = wid * 1024 + 512;

  f32x4 acc1[4][4], acc3[4][4];
#pragma unroll
  for (int i = 0; i < 4; ++i)
#pragma unroll
    for (int j = 0; j < 4; ++j) {
      acc1[i][j] = f32x4{0.f, 0.f, 0.f, 0.f};
      acc3[i][j] = f32x4{0.f, 0.f, 0.f, 0.f};
    }

#define STAGE1(K0, BUF)                                   \
  do {                                                    \
    int bo = (BUF) * 4096;                                \
    g2l16(aG0 + (K0), As + bo + lofs0);                   \
    g2l16(aG1 + (K0), As + bo + lofs1);                   \
    g2l16(b1G0 + (K0), B1s + bo + lofs0);                 \
    g2l16(b1G1 + (K0), B1s + bo + lofs1);                 \
    g2l16(b3G0 + (K0), B3s + bo + lofs0);                 \
    g2l16(b3G1 + (K0), B3s + bo + lofs1);                 \
  } while (0)

  STAGE1(0, 0);
  __syncthreads();          // vmcnt(0) drain: buf0 ready
  int cur = 0;

  const int NK = DIM / 32;
  for (int ks = 0; ks < NK; ++ks) {
    if (ks + 1 < NK) STAGE1((ks + 1) * 32, cur ^ 1);   // in flight under compute

    int bo = cur * 4096;
    bf16x8 a[4], b1[4], b3[4];
#pragma unroll
    for (int f = 0; f < 4; ++f) {
      a[f]  = *(const bf16x8*)(As  + bo + (wr + f * 16 + lr) * 32 + lk);
      b1[f] = *(const bf16x8*)(B1s + bo + (wc + f * 16 + lr) * 32 + lk);
      b3[f] = *(const bf16x8*)(B3s + bo + (wc + f * 16 + lr) * 32 + lk);
    }
#pragma unroll
    for (int i = 0; i < 4; ++i)
#pragma unroll
      for (int j = 0; j < 4; ++j) {
        acc1[i][j] = __builtin_amdgcn_mfma_f32_16x16x32_bf16(a[i], b1[j], acc1[i][j], 0, 0, 0);
        acc3[i][j] = __builtin_amdgcn_mfma_f32_16x16x32_bf16(a[i], b3[j], acc3[i][j], 0, 0, 0);
      }
    __syncthreads();        // drains vmcnt(0): next buf ready; all readers done with cur
    cur ^= 1;
  }

  int base = offs[e];
#pragma unroll
  for (int i = 0; i < 4; ++i)
#pragma unroll
    for (int q = 0; q < 4; ++q) {
      int pl = m0 + wr + i * 16 + (lane >> 4) * 4 + q;
      if (pl >= c) continue;
      unsigned short* hrow = hbuf + (size_t)(base + pl) * HID + n0 + wc + (lane & 15);
#pragma unroll
      for (int j = 0; j < 4; ++j) {
        float v1 = acc1[i][j][q];
        float v3 = acc3[i][j][q];
        float hv = v1 / (1.0f + __expf(-v1)) * v3;   // silu(v1) * v3
        hrow[j * 16] = f2bf(hv);
      }
    }
}

// ---------------- GEMM2: out[tok] += w * (h @ w2) ----------------
__global__ __launch_bounds__(256) void gemm2_kernel(const unsigned short* __restrict__ hbuf,
                                                    const unsigned short* __restrict__ w2t,
                                                    const int* __restrict__ cnt,
                                                    const int* __restrict__ offs,
                                                    const int* __restrict__ idx,
                                                    const float* __restrict__ wgt,
                                                    float* __restrict__ out) {
  int bid = blockIdx.x;
  int e = bid & 7;
  int g = bid >> 3;
  int n0 = (g >> 6) * 128;        // 8 n-tiles, slow
  int m0 = (g & 63) * 128;        // 64 m-slots, fast
  int c = cnt[e];
  if (m0 >= c) return;

  __shared__ __align__(16) unsigned short As[2 * 4096];
  __shared__ __align__(16) unsigned short Bs[2 * 4096];

  int t = threadIdx.x;
  int wid = t >> 6, lane = t & 63;
  int wr = (wid >> 1) * 64, wc = (wid & 1) * 64;
  int lr = lane & 15, lk = (lane >> 4) * 8;
  int base = offs[e];

  int sr0 = wid * 32 + (lane >> 2);
  int sr1 = sr0 + 16;
  int sb = (lane & 3) * 8;
  size_t ha0 = (size_t)imin(base + m0 + sr0, 2 * T_TOK - 1) * HID;
  size_t ha1 = (size_t)imin(base + m0 + sr1, 2 * T_TOK - 1) * HID;
  const unsigned short* aG0 = hbuf + ha0 + sb;
  const unsigned short* aG1 = hbuf + ha1 + sb;
  const unsigned short* w2e = w2t + ((size_t)e * DIM + n0) * HID;
  const unsigned short* bG0 = w2e + (size_t)sr0 * HID + sb;
  const unsigned short* bG1 = w2e + (size_t)sr1 * HID + sb;
  int lofs0 = wid * 1024;
  int lofs1 = wid * 1024 + 512;

  f32x4 acc[4][4];
#pragma unroll
  for (int i = 0; i < 4; ++i)
#pragma unroll
    for (int j = 0; j < 4; ++j) acc[i][j] = f32x4{0.f, 0.f, 0.f, 0.f};

#define STAGE2(K0, BUF)                                   \
  do {                                                    \
    int bo = (BUF) * 4096;                                \
    g2l16(aG0 + (K0), As + bo + lofs0);                   \
    g2l16(aG1 + (K0), As + bo + lofs1);                   \
    g2l16(bG0 + (K0), Bs + bo + lofs0);                   \
    g2l16(bG1 + (K0), Bs + bo + lofs1);                   \
  } while (0)

  STAGE2(0, 0);
  __syncthreads();
  int cur = 0;

  const int NK = HID / 32;
  for (int ks = 0; ks < NK; ++ks) {
    if (ks + 1 < NK) STAGE2((ks + 1) * 32, cur ^ 1);

    int bo = cur * 4096;
    bf16x8 a[4], b[4];
#pragma unroll
    for (int f = 0; f < 4; ++f) {
      a[f] = *(const bf16x8*)(As + bo + (wr + f * 16 + lr) * 32 + lk);
      b[f] = *(const bf16x8*)(Bs + bo + (wc + f * 16 + lr) * 32 + lk);
    }
#pragma unroll
    for (int i = 0; i < 4; ++i)
#pragma unroll
      for (int j = 0; j < 4; ++j)
        acc[i][j] = __builtin_amdgcn_mfma_f32_16x16x32_bf16(a[i], b[j], acc[i][j], 0, 0, 0);
    __syncthreads();
    cur ^= 1;
  }

  const int* idx_e = idx + e * T_TOK;
  const float* wgt_e = wgt + e * T_TOK;
#pragma unroll
  for (int i = 0; i < 4; ++i)
#pragma unroll
    for (int q = 0; q < 4; ++q) {
      int pl = m0 + wr + i * 16 + (lane >> 4) * 4 + q;
      if (pl >= c) continue;
      int tok = idx_e[pl];
      float w = wgt_e[pl];
      float* orow = out + (size_t)tok * DIM + n0 + wc + (lane & 15);
#pragma unroll
      for (int j = 0; j < 4; ++j)
        atomicAdd(orow + j * 16, w * acc[i][j][q]);
    }
}

extern "C" void kernel_launch(void* const* d_in, const int* in_sizes, int n_in,
                              void* d_out, int out_size, void* d_ws, size_t ws_size,
                              hipStream_t stream) {
  const float* x  = (const float*)d_in[0];
  const float* gw = (const float*)d_in[1];
  const float* w1 = (const float*)d_in[2];
  const float* w2 = (const float*)d_in[3];
  const float* w3 = (const float*)d_in[4];
  float* out = (float*)d_out;

  // Workspace layout (~248 MB total)
  char* ws = (char*)d_ws;
  size_t off = 0;
  auto alloc = [&](size_t bytes) {
    char* p = ws + off;
    off += (bytes + 255) & ~(size_t)255;
    return p;
  };
  unsigned short* xb  = (unsigned short*)alloc((size_t)T_TOK * DIM * 2);       // 16.8 MB
  unsigned short* w1t = (unsigned short*)alloc((size_t)NE * DIM * HID * 2);    // 46.1 MB  [E][H][D]
  unsigned short* w3t = (unsigned short*)alloc((size_t)NE * DIM * HID * 2);    // 46.1 MB  [E][H][D]
  unsigned short* w2t = (unsigned short*)alloc((size_t)NE * DIM * HID * 2);    // 46.1 MB  [E][D][H]
  unsigned short* hb  = (unsigned short*)alloc((size_t)2 * T_TOK * HID * 2);   // 92.3 MB
  int*   cnt  = (int*)alloc(NE * sizeof(int));
  int*   offs = (int*)alloc(NE * sizeof(int));
  int*   idx  = (int*)alloc((size_t)NE * T_TOK * sizeof(int));
  float* wgt  = (float*)alloc((size_t)NE * T_TOK * sizeof(float));

  hipMemsetAsync(d_out, 0, (size_t)out_size * sizeof(float), stream);
  hipMemsetAsync(cnt, 0, NE * sizeof(int), stream);

  cast_x_kernel<<<(T_TOK * DIM) / (256 * 8), 256, 0, stream>>>(x, xb);
  transpose_cast_kernel<<<dim3(HID / 32, DIM / 32, NE), 256, 0, stream>>>(w1, w1t, DIM, HID);
  transpose_cast_kernel<<<dim3(HID / 32, DIM / 32, NE), 256, 0, stream>>>(w3, w3t, DIM, HID);
  transpose_cast_kernel<<<dim3(DIM / 32, HID / 32, NE), 256, 0, stream>>>(w2, w2t, HID, DIM);
  router_kernel<<<T_TOK / 4, 256, 0, stream>>>(x, gw, cnt, idx, wgt);
  offsets_kernel<<<1, 64, 0, stream>>>(cnt, offs);

  gemm1_kernel<<<8 * (HID / 128) * 64, 256, 0, stream>>>(xb, w1t, w3t, cnt, offs, idx, hb);
  gemm2_kernel<<<8 * (DIM / 128) * 64, 256, 0, stream>>>(hb, w2t, cnt, offs, idx, wgt, out);
}